// Round 2
// baseline (773.760 us; speedup 1.0000x reference)
//
#include <hip/hip_runtime.h>

#define N_NODES 50000
#define N_EDGES 800000
#define D 128

// ---------------------------------------------------------------------------
// Kernel 1: edge scatter-add.  out[dst[e]] += x[src[e]]  (out pre-zeroed)
// One 64-lane wave per edge; each lane handles 2 consecutive floats (float2
// load, two fp32 atomicAdds -> global_atomic_add_f32, device scope).
// ---------------------------------------------------------------------------
__global__ __launch_bounds__(256) void scatter_kernel(
    const float* __restrict__ x,
    const int* __restrict__ src,
    const int* __restrict__ dst,
    float* __restrict__ out) {
  int gtid = blockIdx.x * 256 + threadIdx.x;
  int e = gtid >> 6;          // wave id = edge id
  int lane = threadIdx.x & 63;
  if (e >= N_EDGES) return;
  int s = src[e];
  int d = dst[e];
  const float2* xr = (const float2*)(x + (size_t)s * D);
  float2 v = xr[lane];
  float* orow = out + (size_t)d * D + lane * 2;
  atomicAdd(orow + 0, v.x);
  atomicAdd(orow + 1, v.y);
}

// ---------------------------------------------------------------------------
// Kernel 2: in-place per-row transform  out[n,:] = h[n,:] @ W^T + b
// Each block exclusively owns RPB=32 rows: stage rows in LDS, then for each
// 64-column half of W, stage W-half transposed in LDS and compute with
// register blocking (2 rows x 4 cols per thread).  No cross-block hazard.
// LDS: 16KB (Hs) + 34KB (Wt padded) = 50.8KB  -> 3 blocks/CU.
// ---------------------------------------------------------------------------
__device__ __forceinline__ void fma4(float4& acc, float s, const float4& wv) {
  acc.x = fmaf(s, wv.x, acc.x);
  acc.y = fmaf(s, wv.y, acc.y);
  acc.z = fmaf(s, wv.z, acc.z);
  acc.w = fmaf(s, wv.w, acc.w);
}

__global__ __launch_bounds__(256) void transform_kernel(
    float* __restrict__ out,
    const float* __restrict__ W,
    const float* __restrict__ bias) {
  constexpr int RPB = 32;   // rows per block
  constexpr int WP = 68;    // padded leading dim for transposed W half (64+4)
  __shared__ float Hs[RPB][D];   // 16 KB
  __shared__ float Wt[D][WP];    // 34 KB; Wt[k][oc] = W[half*64+oc][k]

  int t = threadIdx.x;
  int row0 = blockIdx.x * RPB;
  int tx = t & 15;    // 16 col-groups of 4 -> 64 cols
  int ty = t >> 4;    // 16 row-groups of 2 -> 32 rows

  // Stage this block's rows (contiguous float4 copy; rows exclusively owned).
  int nr = min(RPB, N_NODES - row0);
  {
    const float4* src4 = (const float4*)(out + (size_t)row0 * D);
    float4* dst4 = (float4*)&Hs[0][0];
    for (int i = t; i < nr * (D / 4); i += 256) dst4[i] = src4[i];
  }

  int r0i = ty * 2;
  int r1i = ty * 2 + 1;
  int gr0 = row0 + r0i;
  int gr1 = row0 + r1i;

  for (int half = 0; half < 2; ++half) {
    if (half) __syncthreads();  // prior compute's Wt reads done before overwrite
    // Stage W[half*64 .. half*64+64) transposed via 4x4 register tiles.
    // 16 oc-tiles x 32 k-tiles = 512 tiles, 2 per thread.
    for (int i = t; i < 512; i += 256) {
      int oc0 = (i & 15) * 4;
      int k0 = (i >> 4) * 4;
      const float* wbase = W + (size_t)(half * 64 + oc0) * D + k0;
      float4 a0 = *(const float4*)(wbase + 0 * D);
      float4 a1 = *(const float4*)(wbase + 1 * D);
      float4 a2 = *(const float4*)(wbase + 2 * D);
      float4 a3 = *(const float4*)(wbase + 3 * D);
      Wt[k0 + 0][oc0 + 0] = a0.x; Wt[k0 + 0][oc0 + 1] = a1.x;
      Wt[k0 + 0][oc0 + 2] = a2.x; Wt[k0 + 0][oc0 + 3] = a3.x;
      Wt[k0 + 1][oc0 + 0] = a0.y; Wt[k0 + 1][oc0 + 1] = a1.y;
      Wt[k0 + 1][oc0 + 2] = a2.y; Wt[k0 + 1][oc0 + 3] = a3.y;
      Wt[k0 + 2][oc0 + 0] = a0.z; Wt[k0 + 2][oc0 + 1] = a1.z;
      Wt[k0 + 2][oc0 + 2] = a2.z; Wt[k0 + 2][oc0 + 3] = a3.z;
      Wt[k0 + 3][oc0 + 0] = a0.w; Wt[k0 + 3][oc0 + 1] = a1.w;
      Wt[k0 + 3][oc0 + 2] = a2.w; Wt[k0 + 3][oc0 + 3] = a3.w;
    }
    __syncthreads();

    float4 acc0 = {0.f, 0.f, 0.f, 0.f};
    float4 acc1 = {0.f, 0.f, 0.f, 0.f};
#pragma unroll 4
    for (int k = 0; k < D; k += 4) {
      float4 w0 = *(const float4*)&Wt[k + 0][tx * 4];
      float4 w1 = *(const float4*)&Wt[k + 1][tx * 4];
      float4 w2 = *(const float4*)&Wt[k + 2][tx * 4];
      float4 w3 = *(const float4*)&Wt[k + 3][tx * 4];
      float4 ha = *(const float4*)&Hs[r0i][k];
      float4 hb = *(const float4*)&Hs[r1i][k];
      fma4(acc0, ha.x, w0); fma4(acc0, ha.y, w1);
      fma4(acc0, ha.z, w2); fma4(acc0, ha.w, w3);
      fma4(acc1, hb.x, w0); fma4(acc1, hb.y, w1);
      fma4(acc1, hb.z, w2); fma4(acc1, hb.w, w3);
    }

    float4 bv = *(const float4*)(bias + half * 64 + tx * 4);
    acc0.x += bv.x; acc0.y += bv.y; acc0.z += bv.z; acc0.w += bv.w;
    acc1.x += bv.x; acc1.y += bv.y; acc1.z += bv.z; acc1.w += bv.w;

    if (gr0 < N_NODES)
      ((float4*)(out + (size_t)gr0 * D + half * 64))[tx] = acc0;
    if (gr1 < N_NODES)
      ((float4*)(out + (size_t)gr1 * D + half * 64))[tx] = acc1;
  }
}

extern "C" void kernel_launch(void* const* d_in, const int* in_sizes, int n_in,
                              void* d_out, int out_size, void* d_ws, size_t ws_size,
                              hipStream_t stream) {
  const float* x = (const float*)d_in[0];
  const int* src = (const int*)d_in[1];
  const int* dst = (const int*)d_in[2];
  const float* W = (const float*)d_in[3];
  const float* b = (const float*)d_in[4];
  float* out = (float*)d_out;

  // h accumulator lives in d_out (harness poisons it; zero it ourselves).
  hipMemsetAsync(out, 0, (size_t)N_NODES * D * sizeof(float), stream);

  // One wave per edge, 4 waves per block.
  scatter_kernel<<<N_EDGES / 4, 256, 0, stream>>>(x, src, dst, out);

  // In-place row transform: 32 rows per block.
  transform_kernel<<<(N_NODES + 31) / 32, 256, 0, stream>>>(out, W, b);
}

// Round 3
// 443.122 us; speedup vs baseline: 1.7462x; 1.7462x over previous
//
#include <hip/hip_runtime.h>

#define N_NODES 50000
#define N_EDGES 800000
#define D 128

// ===========================================================================
// CSR build path: hist -> scan -> fill -> gather (no fp32 atomics)
// ===========================================================================

__global__ __launch_bounds__(256) void hist_kernel(
    const int* __restrict__ dst, int* __restrict__ counts) {
  int e = blockIdx.x * 256 + threadIdx.x;
  if (e < N_EDGES) atomicAdd(&counts[dst[e]], 1);
}

// Single-block exclusive scan of counts[50000] -> offsets[50001], cursor[50000].
#define SCAN_T 1024
#define SCAN_CHUNK 49  // 1024*49 = 50176 >= 50000
__global__ __launch_bounds__(SCAN_T) void scan_kernel(
    const int* __restrict__ counts, int* __restrict__ offsets,
    int* __restrict__ cursor) {
  __shared__ int part[SCAN_T];
  int t = threadIdx.x;
  int begin = t * SCAN_CHUNK;
  int end = min(begin + SCAN_CHUNK, N_NODES);
  int s = 0;
  for (int i = begin; i < end; ++i) s += counts[i];
  part[t] = s;
  __syncthreads();
  // Hillis-Steele inclusive scan over 1024 partials.
  for (int off = 1; off < SCAN_T; off <<= 1) {
    int tmp = 0;
    if (t >= off) tmp = part[t - off];
    __syncthreads();
    if (t >= off) part[t] += tmp;
    __syncthreads();
  }
  int base = (t > 0) ? part[t - 1] : 0;  // exclusive base for this chunk
  for (int i = begin; i < end; ++i) {
    offsets[i] = base;
    cursor[i] = base;
    base += counts[i];
  }
  if (t == SCAN_T - 1) offsets[N_NODES] = part[SCAN_T - 1];
}

__global__ __launch_bounds__(256) void fill_kernel(
    const int* __restrict__ src, const int* __restrict__ dst,
    int* __restrict__ cursor, int* __restrict__ esrc) {
  int e = blockIdx.x * 256 + threadIdx.x;
  if (e >= N_EDGES) return;
  int pos = atomicAdd(&cursor[dst[e]], 1);
  esrc[pos] = src[e];
}

// One wave per node: h[n,:] = sum_{e in CSR[n]} x[esrc[e], :]
// Lane covers 2 consecutive floats (8B); 4-deep unroll for latency hiding.
__global__ __launch_bounds__(256) void gather_kernel(
    const float* __restrict__ x, const int* __restrict__ esrc,
    const int* __restrict__ offsets, float* __restrict__ out) {
  int node = blockIdx.x * 4 + (threadIdx.x >> 6);
  int lane = threadIdx.x & 63;
  if (node >= N_NODES) return;
  int beg = offsets[node];
  int end = offsets[node + 1];
  float2 a0 = {0.f, 0.f}, a1 = {0.f, 0.f}, a2 = {0.f, 0.f}, a3 = {0.f, 0.f};
  int i = beg;
  for (; i + 4 <= end; i += 4) {
    int s0 = esrc[i + 0], s1 = esrc[i + 1], s2 = esrc[i + 2], s3 = esrc[i + 3];
    float2 v0 = *(const float2*)(x + (size_t)s0 * D + lane * 2);
    float2 v1 = *(const float2*)(x + (size_t)s1 * D + lane * 2);
    float2 v2 = *(const float2*)(x + (size_t)s2 * D + lane * 2);
    float2 v3 = *(const float2*)(x + (size_t)s3 * D + lane * 2);
    a0.x += v0.x; a0.y += v0.y;
    a1.x += v1.x; a1.y += v1.y;
    a2.x += v2.x; a2.y += v2.y;
    a3.x += v3.x; a3.y += v3.y;
  }
  for (; i < end; ++i) {
    int s = esrc[i];
    float2 v = *(const float2*)(x + (size_t)s * D + lane * 2);
    a0.x += v.x; a0.y += v.y;
  }
  float2 r;
  r.x = (a0.x + a1.x) + (a2.x + a3.x);
  r.y = (a0.y + a1.y) + (a2.y + a3.y);
  *(float2*)(out + (size_t)node * D + lane * 2) = r;
}

// ===========================================================================
// Fallback (ws too small): atomic scatter into pre-zeroed out.
// ===========================================================================
__global__ __launch_bounds__(256) void scatter_kernel(
    const float* __restrict__ x, const int* __restrict__ src,
    const int* __restrict__ dst, float* __restrict__ out) {
  int gtid = blockIdx.x * 256 + threadIdx.x;
  int e = gtid >> 6;
  int lane = threadIdx.x & 63;
  if (e >= N_EDGES) return;
  int s = src[e];
  int d = dst[e];
  float2 v = ((const float2*)(x + (size_t)s * D))[lane];
  float* orow = out + (size_t)d * D + lane * 2;
  atomicAdd(orow + 0, v.x);
  atomicAdd(orow + 1, v.y);
}

// ===========================================================================
// Transform v2 (in place): out[n,:] = h[n,:] @ W^T + b
// RPB=64 rows staged in LDS (padded ld=132 -> bank shift 4/row).  W read
// directly from global (L1/L2-hot broadcast).  4 rows x 4 cols per thread,
// dot-product form: 8 x float4 loads per 64 FMA.
// ===========================================================================
__global__ __launch_bounds__(256) void transform_kernel(
    float* __restrict__ out, const float* __restrict__ W,
    const float* __restrict__ bias) {
  constexpr int RPB = 64;
  constexpr int HP = 132;
  __shared__ float Hs[RPB][HP];  // 33 KB

  int t = threadIdx.x;
  int row0 = blockIdx.x * RPB;
  int nr = min(RPB, N_NODES - row0);

  // Stage rows (coalesced float4; rows exclusively owned by this block).
  {
    const float4* g = (const float4*)(out + (size_t)row0 * D);
    for (int i = t; i < nr * (D / 4); i += 256) {
      int r = i >> 5;          // 32 float4 per row
      int c = (i & 31) * 4;
      *(float4*)&Hs[r][c] = g[i];
    }
  }
  __syncthreads();

  int tx = t & 15;   // 16 col groups of 4
  int ty = t >> 4;   // 16 row groups of 4
  int r0 = ty * 4;

  for (int half = 0; half < 2; ++half) {
    int oc0 = half * 64 + tx * 4;
    const float* Wb = W + (size_t)oc0 * D;
    float4 a0 = {0.f, 0.f, 0.f, 0.f};
    float4 a1 = {0.f, 0.f, 0.f, 0.f};
    float4 a2 = {0.f, 0.f, 0.f, 0.f};
    float4 a3 = {0.f, 0.f, 0.f, 0.f};
#pragma unroll 8
    for (int k = 0; k < D; k += 4) {
      float4 w0 = *(const float4*)(Wb + 0 * D + k);
      float4 w1 = *(const float4*)(Wb + 1 * D + k);
      float4 w2 = *(const float4*)(Wb + 2 * D + k);
      float4 w3 = *(const float4*)(Wb + 3 * D + k);
      float4 h0 = *(const float4*)&Hs[r0 + 0][k];
      float4 h1 = *(const float4*)&Hs[r0 + 1][k];
      float4 h2 = *(const float4*)&Hs[r0 + 2][k];
      float4 h3 = *(const float4*)&Hs[r0 + 3][k];
#define DOT(hv, wv) fmaf((hv).w, (wv).w, fmaf((hv).z, (wv).z, fmaf((hv).y, (wv).y, (hv).x * (wv).x)))
      a0.x += DOT(h0, w0); a0.y += DOT(h0, w1); a0.z += DOT(h0, w2); a0.w += DOT(h0, w3);
      a1.x += DOT(h1, w0); a1.y += DOT(h1, w1); a1.z += DOT(h1, w2); a1.w += DOT(h1, w3);
      a2.x += DOT(h2, w0); a2.y += DOT(h2, w1); a2.z += DOT(h2, w2); a2.w += DOT(h2, w3);
      a3.x += DOT(h3, w0); a3.y += DOT(h3, w1); a3.z += DOT(h3, w2); a3.w += DOT(h3, w3);
#undef DOT
    }
    float4 bv = *(const float4*)(bias + oc0);
    a0.x += bv.x; a0.y += bv.y; a0.z += bv.z; a0.w += bv.w;
    a1.x += bv.x; a1.y += bv.y; a1.z += bv.z; a1.w += bv.w;
    a2.x += bv.x; a2.y += bv.y; a2.z += bv.z; a2.w += bv.w;
    a3.x += bv.x; a3.y += bv.y; a3.z += bv.z; a3.w += bv.w;

    if (r0 + 0 < nr) *(float4*)(out + (size_t)(row0 + r0 + 0) * D + oc0) = a0;
    if (r0 + 1 < nr) *(float4*)(out + (size_t)(row0 + r0 + 1) * D + oc0) = a1;
    if (r0 + 2 < nr) *(float4*)(out + (size_t)(row0 + r0 + 2) * D + oc0) = a2;
    if (r0 + 3 < nr) *(float4*)(out + (size_t)(row0 + r0 + 3) * D + oc0) = a3;
  }
}

extern "C" void kernel_launch(void* const* d_in, const int* in_sizes, int n_in,
                              void* d_out, int out_size, void* d_ws, size_t ws_size,
                              hipStream_t stream) {
  const float* x = (const float*)d_in[0];
  const int* src = (const int*)d_in[1];
  const int* dst = (const int*)d_in[2];
  const float* W = (const float*)d_in[3];
  const float* b = (const float*)d_in[4];
  float* out = (float*)d_out;

  const size_t A = 50048;  // ints per small array slot (aligned)
  size_t needed = (3 * A + (size_t)N_EDGES) * sizeof(int);

  if (ws_size >= needed) {
    int* counts  = (int*)d_ws;
    int* offsets = counts + A;       // 50001 used
    int* cursor  = offsets + A;
    int* esrc    = cursor + A;

    hipMemsetAsync(counts, 0, N_NODES * sizeof(int), stream);
    hist_kernel<<<(N_EDGES + 255) / 256, 256, 0, stream>>>(dst, counts);
    scan_kernel<<<1, SCAN_T, 0, stream>>>(counts, offsets, cursor);
    fill_kernel<<<(N_EDGES + 255) / 256, 256, 0, stream>>>(src, dst, cursor, esrc);
    gather_kernel<<<(N_NODES + 3) / 4, 256, 0, stream>>>(x, esrc, offsets, out);
  } else {
    // Fallback: fp32 atomic scatter.
    hipMemsetAsync(out, 0, (size_t)N_NODES * D * sizeof(float), stream);
    scatter_kernel<<<N_EDGES / 4, 256, 0, stream>>>(x, src, dst, out);
  }

  transform_kernel<<<(N_NODES + 63) / 64, 256, 0, stream>>>(out, W, b);
}

// Round 4
// 345.976 us; speedup vs baseline: 2.2365x; 1.2808x over previous
//
#include <hip/hip_runtime.h>

#define N_NODES 50000
#define N_EDGES 800000
#define D 128

typedef __attribute__((ext_vector_type(8))) short bf16x8;   // MFMA A/B frag
typedef __attribute__((ext_vector_type(4))) float floatx4;  // MFMA C/D frag

__device__ __forceinline__ unsigned short f2bf(float f) {
  unsigned u = __builtin_bit_cast(unsigned, f);
  unsigned r = u + 0x7FFFu + ((u >> 16) & 1u);  // RNE
  return (unsigned short)(r >> 16);
}

// ===========================================================================
// CSR build: hist -> scan -> fill
// ===========================================================================
__global__ __launch_bounds__(256) void hist_kernel(
    const int* __restrict__ dst, int* __restrict__ counts) {
  int e = blockIdx.x * 256 + threadIdx.x;
  if (e < N_EDGES) atomicAdd(&counts[dst[e]], 1);
}

#define SCAN_T 1024
#define SCAN_CHUNK 49  // 1024*49 = 50176 >= 50000
__global__ __launch_bounds__(SCAN_T) void scan_kernel(
    const int* __restrict__ counts, int* __restrict__ offsets,
    int* __restrict__ cursor) {
  __shared__ int part[SCAN_T];
  int t = threadIdx.x;
  int begin = t * SCAN_CHUNK;
  int end = min(begin + SCAN_CHUNK, N_NODES);
  int s = 0;
  for (int i = begin; i < end; ++i) s += counts[i];
  part[t] = s;
  __syncthreads();
  for (int off = 1; off < SCAN_T; off <<= 1) {
    int tmp = 0;
    if (t >= off) tmp = part[t - off];
    __syncthreads();
    if (t >= off) part[t] += tmp;
    __syncthreads();
  }
  int base = (t > 0) ? part[t - 1] : 0;
  for (int i = begin; i < end; ++i) {
    offsets[i] = base;
    cursor[i] = base;
    base += counts[i];
  }
  if (t == SCAN_T - 1) offsets[N_NODES] = part[SCAN_T - 1];
}

__global__ __launch_bounds__(256) void fill_kernel(
    const int* __restrict__ src, const int* __restrict__ dst,
    int* __restrict__ cursor, int* __restrict__ esrc) {
  int e = blockIdx.x * 256 + threadIdx.x;
  if (e >= N_EDGES) return;
  int pos = atomicAdd(&cursor[dst[e]], 1);
  esrc[pos] = src[e];
}

// ===========================================================================
// GEMM: y[50000,128] = x[50000,128] @ W^T   (bf16 MFMA, f32 accumulate)
// Block = 256 threads (4 waves), tile = 128 rows x 128 cols, K = 128.
// W is [out,in] row-major == B-operand [n][k] layout directly.
// LDS ld = 136 bf16 (272 B row stride -> bank shift 4/row, 2-way free).
// ===========================================================================
#define LDA 136
__global__ __launch_bounds__(256) void gemm_xw(
    const float* __restrict__ x, const float* __restrict__ W,
    float* __restrict__ y) {
  __shared__ unsigned short As[128 * LDA];  // x tile, [m][k] bf16
  __shared__ unsigned short Ws[128 * LDA];  // W,      [n][k] bf16

  int t = threadIdx.x;
  int row0 = blockIdx.x * 128;

  // Stage x tile (f32 -> bf16) and W. 4096 float4 each, 16/thread.
  for (int i = t; i < 4096; i += 256) {
    int r = i >> 5;
    int c4 = (i & 31) * 4;
    int gr = row0 + r;
    float4 v = (gr < N_NODES) ? *(const float4*)(x + (size_t)gr * D + c4)
                              : float4{0.f, 0.f, 0.f, 0.f};
    unsigned short* p = &As[r * LDA + c4];
    p[0] = f2bf(v.x); p[1] = f2bf(v.y); p[2] = f2bf(v.z); p[3] = f2bf(v.w);
    float4 wv = *(const float4*)(W + (size_t)r * D + c4);
    unsigned short* q = &Ws[r * LDA + c4];
    q[0] = f2bf(wv.x); q[1] = f2bf(wv.y); q[2] = f2bf(wv.z); q[3] = f2bf(wv.w);
  }
  __syncthreads();

  int w = t >> 6;          // wave id: rows [w*32, w*32+32)
  int lane = t & 63;
  int ln = lane & 15;      // m (A) / n (B) / col (D)
  int quad = lane >> 4;    // k-group (A,B) / row-group (D)

  floatx4 acc[2][8];
#pragma unroll
  for (int m = 0; m < 2; ++m)
#pragma unroll
    for (int n = 0; n < 8; ++n) acc[m][n] = floatx4{0.f, 0.f, 0.f, 0.f};

#pragma unroll
  for (int ks = 0; ks < 4; ++ks) {
    int kc = ks * 32 + quad * 8;
    bf16x8 a0 = *(const bf16x8*)&As[(w * 32 + ln) * LDA + kc];
    bf16x8 a1 = *(const bf16x8*)&As[(w * 32 + 16 + ln) * LDA + kc];
#pragma unroll
    for (int n = 0; n < 8; ++n) {
      bf16x8 bf = *(const bf16x8*)&Ws[(n * 16 + ln) * LDA + kc];
      acc[0][n] = __builtin_amdgcn_mfma_f32_16x16x32_bf16(a0, bf, acc[0][n], 0, 0, 0);
      acc[1][n] = __builtin_amdgcn_mfma_f32_16x16x32_bf16(a1, bf, acc[1][n], 0, 0, 0);
    }
  }

  // D layout: col = lane&15, row = quad*4 + reg.
#pragma unroll
  for (int m = 0; m < 2; ++m) {
    int gr0 = row0 + w * 32 + m * 16 + quad * 4;
#pragma unroll
    for (int n = 0; n < 8; ++n) {
      int gc = n * 16 + ln;
#pragma unroll
      for (int r = 0; r < 4; ++r) {
        int gr = gr0 + r;
        if (gr < N_NODES) y[(size_t)gr * D + gc] = acc[m][n][r];
      }
    }
  }
}

// ===========================================================================
// Gather: out[v,:] = b + sum_{e: dst==v} y[esrc[e], :]
// One wave per node; each 32-lane half handles alternate edges with float4
// loads (dwordx4), 2-deep unroll; cross-half reduce via shfl_xor(32).
// ===========================================================================
__global__ __launch_bounds__(256) void gather_y_kernel(
    const float* __restrict__ y, const int* __restrict__ esrc,
    const int* __restrict__ offsets, const float* __restrict__ bias,
    float* __restrict__ out) {
  int node = blockIdx.x * 4 + (threadIdx.x >> 6);
  if (node >= N_NODES) return;
  int lane = threadIdx.x & 63;
  int half = lane >> 5;
  int l = lane & 31;
  int beg = offsets[node];
  int end = offsets[node + 1];

  float4 a0 = {0.f, 0.f, 0.f, 0.f};
  float4 a1 = {0.f, 0.f, 0.f, 0.f};
  int i = beg + half;
  for (; i + 2 < end; i += 4) {
    int s0 = esrc[i];
    int s1 = esrc[i + 2];
    float4 v0 = *(const float4*)(y + (size_t)s0 * D + l * 4);
    float4 v1 = *(const float4*)(y + (size_t)s1 * D + l * 4);
    a0.x += v0.x; a0.y += v0.y; a0.z += v0.z; a0.w += v0.w;
    a1.x += v1.x; a1.y += v1.y; a1.z += v1.z; a1.w += v1.w;
  }
  if (i < end) {
    int s = esrc[i];
    float4 v = *(const float4*)(y + (size_t)s * D + l * 4);
    a0.x += v.x; a0.y += v.y; a0.z += v.z; a0.w += v.w;
  }
  a0.x += a1.x; a0.y += a1.y; a0.z += a1.z; a0.w += a1.w;

  a0.x += __shfl_xor(a0.x, 32);
  a0.y += __shfl_xor(a0.y, 32);
  a0.z += __shfl_xor(a0.z, 32);
  a0.w += __shfl_xor(a0.w, 32);

  if (half == 0) {
    float4 bv = *(const float4*)(bias + l * 4);
    a0.x += bv.x; a0.y += bv.y; a0.z += bv.z; a0.w += bv.w;
    *(float4*)(out + (size_t)node * D + l * 4) = a0;
  }
}

// ===========================================================================
// Fallback path kernels (ws too small): R3 structure.
// ===========================================================================
__global__ __launch_bounds__(256) void gather_x_kernel(
    const float* __restrict__ x, const int* __restrict__ esrc,
    const int* __restrict__ offsets, float* __restrict__ out) {
  int node = blockIdx.x * 4 + (threadIdx.x >> 6);
  int lane = threadIdx.x & 63;
  if (node >= N_NODES) return;
  int beg = offsets[node];
  int end = offsets[node + 1];
  float2 a0 = {0.f, 0.f}, a1 = {0.f, 0.f};
  int i = beg;
  for (; i + 2 <= end; i += 2) {
    int s0 = esrc[i], s1 = esrc[i + 1];
    float2 v0 = *(const float2*)(x + (size_t)s0 * D + lane * 2);
    float2 v1 = *(const float2*)(x + (size_t)s1 * D + lane * 2);
    a0.x += v0.x; a0.y += v0.y;
    a1.x += v1.x; a1.y += v1.y;
  }
  if (i < end) {
    int s = esrc[i];
    float2 v = *(const float2*)(x + (size_t)s * D + lane * 2);
    a0.x += v.x; a0.y += v.y;
  }
  float2 r;
  r.x = a0.x + a1.x;
  r.y = a0.y + a1.y;
  *(float2*)(out + (size_t)node * D + lane * 2) = r;
}

__global__ __launch_bounds__(256) void scatter_kernel(
    const float* __restrict__ x, const int* __restrict__ src,
    const int* __restrict__ dst, float* __restrict__ out) {
  int gtid = blockIdx.x * 256 + threadIdx.x;
  int e = gtid >> 6;
  int lane = threadIdx.x & 63;
  if (e >= N_EDGES) return;
  float2 v = ((const float2*)(x + (size_t)src[e] * D))[lane];
  float* orow = out + (size_t)dst[e] * D + lane * 2;
  atomicAdd(orow + 0, v.x);
  atomicAdd(orow + 1, v.y);
}

__global__ __launch_bounds__(256) void transform_kernel(
    float* __restrict__ out, const float* __restrict__ W,
    const float* __restrict__ bias) {
  constexpr int RPB = 64;
  constexpr int HP = 132;
  __shared__ float Hs[RPB][HP];
  int t = threadIdx.x;
  int row0 = blockIdx.x * RPB;
  int nr = min(RPB, N_NODES - row0);
  {
    const float4* g = (const float4*)(out + (size_t)row0 * D);
    for (int i = t; i < nr * (D / 4); i += 256) {
      int r = i >> 5;
      int c = (i & 31) * 4;
      *(float4*)&Hs[r][c] = g[i];
    }
  }
  __syncthreads();
  int tx = t & 15;
  int ty = t >> 4;
  int r0 = ty * 4;
  for (int half = 0; half < 2; ++half) {
    int oc0 = half * 64 + tx * 4;
    const float* Wb = W + (size_t)oc0 * D;
    float4 a0 = {0.f, 0.f, 0.f, 0.f}, a1 = {0.f, 0.f, 0.f, 0.f};
    float4 a2 = {0.f, 0.f, 0.f, 0.f}, a3 = {0.f, 0.f, 0.f, 0.f};
#pragma unroll 8
    for (int k = 0; k < D; k += 4) {
      float4 w0 = *(const float4*)(Wb + 0 * D + k);
      float4 w1 = *(const float4*)(Wb + 1 * D + k);
      float4 w2 = *(const float4*)(Wb + 2 * D + k);
      float4 w3 = *(const float4*)(Wb + 3 * D + k);
      float4 h0 = *(const float4*)&Hs[r0 + 0][k];
      float4 h1 = *(const float4*)&Hs[r0 + 1][k];
      float4 h2 = *(const float4*)&Hs[r0 + 2][k];
      float4 h3 = *(const float4*)&Hs[r0 + 3][k];
#define DOT(hv, wv) fmaf((hv).w, (wv).w, fmaf((hv).z, (wv).z, fmaf((hv).y, (wv).y, (hv).x * (wv).x)))
      a0.x += DOT(h0, w0); a0.y += DOT(h0, w1); a0.z += DOT(h0, w2); a0.w += DOT(h0, w3);
      a1.x += DOT(h1, w0); a1.y += DOT(h1, w1); a1.z += DOT(h1, w2); a1.w += DOT(h1, w3);
      a2.x += DOT(h2, w0); a2.y += DOT(h2, w1); a2.z += DOT(h2, w2); a2.w += DOT(h2, w3);
      a3.x += DOT(h3, w0); a3.y += DOT(h3, w1); a3.z += DOT(h3, w2); a3.w += DOT(h3, w3);
#undef DOT
    }
    float4 bv = *(const float4*)(bias + oc0);
    a0.x += bv.x; a0.y += bv.y; a0.z += bv.z; a0.w += bv.w;
    a1.x += bv.x; a1.y += bv.y; a1.z += bv.z; a1.w += bv.w;
    a2.x += bv.x; a2.y += bv.y; a2.z += bv.z; a2.w += bv.w;
    a3.x += bv.x; a3.y += bv.y; a3.z += bv.z; a3.w += bv.w;
    if (r0 + 0 < nr) *(float4*)(out + (size_t)(row0 + r0 + 0) * D + oc0) = a0;
    if (r0 + 1 < nr) *(float4*)(out + (size_t)(row0 + r0 + 1) * D + oc0) = a1;
    if (r0 + 2 < nr) *(float4*)(out + (size_t)(row0 + r0 + 2) * D + oc0) = a2;
    if (r0 + 3 < nr) *(float4*)(out + (size_t)(row0 + r0 + 3) * D + oc0) = a3;
  }
}

extern "C" void kernel_launch(void* const* d_in, const int* in_sizes, int n_in,
                              void* d_out, int out_size, void* d_ws, size_t ws_size,
                              hipStream_t stream) {
  const float* x = (const float*)d_in[0];
  const int* src = (const int*)d_in[1];
  const int* dst = (const int*)d_in[2];
  const float* W = (const float*)d_in[3];
  const float* b = (const float*)d_in[4];
  float* out = (float*)d_out;

  const size_t A = 50048;  // ints per slot (aligned)
  const size_t csr_ints = 3 * A + (size_t)N_EDGES;
  const size_t need_csr = csr_ints * sizeof(int);
  const size_t need_full = need_csr + (size_t)N_NODES * D * sizeof(float);

  if (ws_size >= need_full) {
    int* counts  = (int*)d_ws;
    int* offsets = counts + A;
    int* cursor  = offsets + A;
    int* esrc    = cursor + A;
    float* y     = (float*)(esrc + N_EDGES);

    hipMemsetAsync(counts, 0, N_NODES * sizeof(int), stream);
    hist_kernel<<<(N_EDGES + 255) / 256, 256, 0, stream>>>(dst, counts);
    scan_kernel<<<1, SCAN_T, 0, stream>>>(counts, offsets, cursor);
    fill_kernel<<<(N_EDGES + 255) / 256, 256, 0, stream>>>(src, dst, cursor, esrc);
    gemm_xw<<<(N_NODES + 127) / 128, 256, 0, stream>>>(x, W, y);
    gather_y_kernel<<<(N_NODES + 3) / 4, 256, 0, stream>>>(y, esrc, offsets, b, out);
  } else if (ws_size >= need_csr) {
    int* counts  = (int*)d_ws;
    int* offsets = counts + A;
    int* cursor  = offsets + A;
    int* esrc    = cursor + A;
    hipMemsetAsync(counts, 0, N_NODES * sizeof(int), stream);
    hist_kernel<<<(N_EDGES + 255) / 256, 256, 0, stream>>>(dst, counts);
    scan_kernel<<<1, SCAN_T, 0, stream>>>(counts, offsets, cursor);
    fill_kernel<<<(N_EDGES + 255) / 256, 256, 0, stream>>>(src, dst, cursor, esrc);
    gather_x_kernel<<<(N_NODES + 3) / 4, 256, 0, stream>>>(x, esrc, offsets, out);
    transform_kernel<<<(N_NODES + 63) / 64, 256, 0, stream>>>(out, W, b);
  } else {
    hipMemsetAsync(out, 0, (size_t)N_NODES * D * sizeof(float), stream);
    scatter_kernel<<<N_EDGES / 4, 256, 0, stream>>>(x, src, dst, out);
    transform_kernel<<<(N_NODES + 63) / 64, 256, 0, stream>>>(out, W, b);
  }
}

// Round 5
// 216.717 us; speedup vs baseline: 3.5704x; 1.5964x over previous
//
#include <hip/hip_runtime.h>

#define N_NODES 50000
#define N_EDGES 800000
#define D 128

typedef __attribute__((ext_vector_type(8))) short bf16x8;   // MFMA A/B frag
typedef __attribute__((ext_vector_type(4))) float floatx4;  // MFMA C/D frag

__device__ __forceinline__ unsigned short f2bf(float f) {
  unsigned u = __builtin_bit_cast(unsigned, f);
  unsigned r = u + 0x7FFFu + ((u >> 16) & 1u);  // RNE
  return (unsigned short)(r >> 16);
}
__device__ __forceinline__ float bf2f_lo(unsigned u) {
  return __builtin_bit_cast(float, u << 16);
}
__device__ __forceinline__ float bf2f_hi(unsigned u) {
  return __builtin_bit_cast(float, u & 0xFFFF0000u);
}

// ===========================================================================
// CSR build: hist -> (reduce, scan) -> fill      [scan now fully parallel]
// ===========================================================================
__global__ __launch_bounds__(256) void hist_kernel(
    const int* __restrict__ dst, int* __restrict__ counts) {
  int e = blockIdx.x * 256 + threadIdx.x;
  if (e < N_EDGES) atomicAdd(&counts[dst[e]], 1);
}

#define SBLK 196  // 196*256 = 50176 >= 50000

__global__ __launch_bounds__(256) void reduce_kernel(
    const int* __restrict__ counts, int* __restrict__ blockSums) {
  int i = blockIdx.x * 256 + threadIdx.x;
  int v = (i < N_NODES) ? counts[i] : 0;
#pragma unroll
  for (int off = 32; off; off >>= 1) v += __shfl_down(v, off);
  __shared__ int ws[4];
  int lane = threadIdx.x & 63, wid = threadIdx.x >> 6;
  if (lane == 0) ws[wid] = v;
  __syncthreads();
  if (threadIdx.x == 0) blockSums[blockIdx.x] = ws[0] + ws[1] + ws[2] + ws[3];
}

__global__ __launch_bounds__(256) void scan_kernel2(
    const int* __restrict__ counts, const int* __restrict__ blockSums,
    int* __restrict__ offsets, int* __restrict__ cursor) {
  int b = blockIdx.x;
  int t = threadIdx.x;
  int lane = t & 63, wid = t >> 6;

  // base = sum of blockSums[0..b)   (b <= 195 < 256: one element per thread)
  int pv = (t < b) ? blockSums[t] : 0;
#pragma unroll
  for (int off = 32; off; off >>= 1) pv += __shfl_down(pv, off);
  __shared__ int ws[4];
  __shared__ int wsum[4];
  __shared__ int base_s;
  if (lane == 0) ws[wid] = pv;
  __syncthreads();
  if (t == 0) base_s = ws[0] + ws[1] + ws[2] + ws[3];

  // block-wide exclusive scan of this block's 256 counts
  int i = b * 256 + t;
  int c = (i < N_NODES) ? counts[i] : 0;
  int v = c;
#pragma unroll
  for (int off = 1; off < 64; off <<= 1) {
    int n = __shfl_up(v, off);
    if (lane >= off) v += n;
  }
  if (lane == 63) wsum[wid] = v;
  __syncthreads();
  int wbase = 0;
  for (int w2 = 0; w2 < wid; ++w2) wbase += wsum[w2];
  int excl = base_s + wbase + v - c;
  if (i < N_NODES) {
    offsets[i] = excl;
    cursor[i] = excl;
    if (i == N_NODES - 1) offsets[N_NODES] = excl + c;  // == N_EDGES
  }
}

__global__ __launch_bounds__(256) void fill_kernel(
    const int* __restrict__ src, const int* __restrict__ dst,
    int* __restrict__ cursor, int* __restrict__ esrc) {
  int e = blockIdx.x * 256 + threadIdx.x;
  if (e >= N_EDGES) return;
  int pos = atomicAdd(&cursor[dst[e]], 1);
  esrc[pos] = src[e];
}

// ===========================================================================
// GEMM: y[50000,128] = bf16( x @ W^T )   (bf16 MFMA, f32 acc, bf16 store)
// Tile 128x128, K=128.  W is [out,in] row-major == B-operand [n][k] directly.
// ===========================================================================
#define LDA 136
__global__ __launch_bounds__(256) void gemm_xw(
    const float* __restrict__ x, const float* __restrict__ W,
    unsigned short* __restrict__ y) {
  __shared__ unsigned short As[128 * LDA];
  __shared__ unsigned short Ws[128 * LDA];

  int t = threadIdx.x;
  int row0 = blockIdx.x * 128;

  for (int i = t; i < 4096; i += 256) {
    int r = i >> 5;
    int c4 = (i & 31) * 4;
    int gr = row0 + r;
    float4 v = (gr < N_NODES) ? *(const float4*)(x + (size_t)gr * D + c4)
                              : float4{0.f, 0.f, 0.f, 0.f};
    unsigned short* p = &As[r * LDA + c4];
    p[0] = f2bf(v.x); p[1] = f2bf(v.y); p[2] = f2bf(v.z); p[3] = f2bf(v.w);
    float4 wv = *(const float4*)(W + (size_t)r * D + c4);
    unsigned short* q = &Ws[r * LDA + c4];
    q[0] = f2bf(wv.x); q[1] = f2bf(wv.y); q[2] = f2bf(wv.z); q[3] = f2bf(wv.w);
  }
  __syncthreads();

  int w = t >> 6;
  int lane = t & 63;
  int ln = lane & 15;
  int quad = lane >> 4;

  floatx4 acc[2][8];
#pragma unroll
  for (int m = 0; m < 2; ++m)
#pragma unroll
    for (int n = 0; n < 8; ++n) acc[m][n] = floatx4{0.f, 0.f, 0.f, 0.f};

#pragma unroll
  for (int ks = 0; ks < 4; ++ks) {
    int kc = ks * 32 + quad * 8;
    bf16x8 a0 = *(const bf16x8*)&As[(w * 32 + ln) * LDA + kc];
    bf16x8 a1 = *(const bf16x8*)&As[(w * 32 + 16 + ln) * LDA + kc];
#pragma unroll
    for (int n = 0; n < 8; ++n) {
      bf16x8 bf = *(const bf16x8*)&Ws[(n * 16 + ln) * LDA + kc];
      acc[0][n] = __builtin_amdgcn_mfma_f32_16x16x32_bf16(a0, bf, acc[0][n], 0, 0, 0);
      acc[1][n] = __builtin_amdgcn_mfma_f32_16x16x32_bf16(a1, bf, acc[1][n], 0, 0, 0);
    }
  }

  // D layout: col = lane&15, row = quad*4 + reg.
#pragma unroll
  for (int m = 0; m < 2; ++m) {
    int gr0 = row0 + w * 32 + m * 16 + quad * 4;
#pragma unroll
    for (int n = 0; n < 8; ++n) {
      int gc = n * 16 + ln;
#pragma unroll
      for (int r = 0; r < 4; ++r) {
        int gr = gr0 + r;
        if (gr < N_NODES) y[(size_t)gr * D + gc] = f2bf(acc[m][n][r]);
      }
    }
  }
}

// ===========================================================================
// Gather: out[v,:] = b + sum_{e: dst==v} y[esrc[e], :]    (y is bf16)
// One wave per node; 4 edges in flight (16-lane groups, each loads a full
// 256 B row as dwordx4); 2-deep unroll; reduce via shfl_xor(16/32).
// ===========================================================================
__global__ __launch_bounds__(256) void gather_ybf_kernel(
    const unsigned short* __restrict__ y, const int* __restrict__ esrc,
    const int* __restrict__ offsets, const float* __restrict__ bias,
    float* __restrict__ out) {
  int node = blockIdx.x * 4 + (threadIdx.x >> 6);
  if (node >= N_NODES) return;
  int lane = threadIdx.x & 63;
  int g = lane >> 4;   // edge subgroup 0..3
  int l = lane & 15;   // 8-element chunk within row
  int beg = offsets[node];
  int end = offsets[node + 1];

  float acc[8] = {0.f, 0.f, 0.f, 0.f, 0.f, 0.f, 0.f, 0.f};
  int i = beg + g;
  for (; i + 4 < end; i += 8) {
    int s0 = esrc[i];
    int s1 = esrc[i + 4];
    uint4 u0 = *(const uint4*)(y + (size_t)s0 * D + l * 8);
    uint4 u1 = *(const uint4*)(y + (size_t)s1 * D + l * 8);
    acc[0] += bf2f_lo(u0.x) + bf2f_lo(u1.x);
    acc[1] += bf2f_hi(u0.x) + bf2f_hi(u1.x);
    acc[2] += bf2f_lo(u0.y) + bf2f_lo(u1.y);
    acc[3] += bf2f_hi(u0.y) + bf2f_hi(u1.y);
    acc[4] += bf2f_lo(u0.z) + bf2f_lo(u1.z);
    acc[5] += bf2f_hi(u0.z) + bf2f_hi(u1.z);
    acc[6] += bf2f_lo(u0.w) + bf2f_lo(u1.w);
    acc[7] += bf2f_hi(u0.w) + bf2f_hi(u1.w);
  }
  if (i < end) {
    int s = esrc[i];
    uint4 u = *(const uint4*)(y + (size_t)s * D + l * 8);
    acc[0] += bf2f_lo(u.x); acc[1] += bf2f_hi(u.x);
    acc[2] += bf2f_lo(u.y); acc[3] += bf2f_hi(u.y);
    acc[4] += bf2f_lo(u.z); acc[5] += bf2f_hi(u.z);
    acc[6] += bf2f_lo(u.w); acc[7] += bf2f_hi(u.w);
  }
#pragma unroll
  for (int j = 0; j < 8; ++j) {
    acc[j] += __shfl_xor(acc[j], 16);
    acc[j] += __shfl_xor(acc[j], 32);
  }
  if (g == 0) {
    const float* bp = bias + l * 8;
    float4 r0 = {acc[0] + bp[0], acc[1] + bp[1], acc[2] + bp[2], acc[3] + bp[3]};
    float4 r1 = {acc[4] + bp[4], acc[5] + bp[5], acc[6] + bp[6], acc[7] + bp[7]};
    float* op = out + (size_t)node * D + l * 8;
    *(float4*)op = r0;
    *(float4*)(op + 4) = r1;
  }
}

// ===========================================================================
// Fallback (ws too small): atomic scatter + f32 transform.
// ===========================================================================
__global__ __launch_bounds__(256) void scatter_kernel(
    const float* __restrict__ x, const int* __restrict__ src,
    const int* __restrict__ dst, float* __restrict__ out) {
  int gtid = blockIdx.x * 256 + threadIdx.x;
  int e = gtid >> 6;
  int lane = threadIdx.x & 63;
  if (e >= N_EDGES) return;
  float2 v = ((const float2*)(x + (size_t)src[e] * D))[lane];
  float* orow = out + (size_t)dst[e] * D + lane * 2;
  atomicAdd(orow + 0, v.x);
  atomicAdd(orow + 1, v.y);
}

__global__ __launch_bounds__(256) void transform_kernel(
    float* __restrict__ out, const float* __restrict__ W,
    const float* __restrict__ bias) {
  constexpr int RPB = 64;
  constexpr int HP = 132;
  __shared__ float Hs[RPB][HP];
  int t = threadIdx.x;
  int row0 = blockIdx.x * RPB;
  int nr = min(RPB, N_NODES - row0);
  {
    const float4* g = (const float4*)(out + (size_t)row0 * D);
    for (int i = t; i < nr * (D / 4); i += 256) {
      int r = i >> 5;
      int c = (i & 31) * 4;
      *(float4*)&Hs[r][c] = g[i];
    }
  }
  __syncthreads();
  int tx = t & 15;
  int ty = t >> 4;
  int r0 = ty * 4;
  for (int half = 0; half < 2; ++half) {
    int oc0 = half * 64 + tx * 4;
    const float* Wb = W + (size_t)oc0 * D;
    float4 a0 = {0.f, 0.f, 0.f, 0.f}, a1 = {0.f, 0.f, 0.f, 0.f};
    float4 a2 = {0.f, 0.f, 0.f, 0.f}, a3 = {0.f, 0.f, 0.f, 0.f};
#pragma unroll 8
    for (int k = 0; k < D; k += 4) {
      float4 w0 = *(const float4*)(Wb + 0 * D + k);
      float4 w1 = *(const float4*)(Wb + 1 * D + k);
      float4 w2 = *(const float4*)(Wb + 2 * D + k);
      float4 w3 = *(const float4*)(Wb + 3 * D + k);
      float4 h0 = *(const float4*)&Hs[r0 + 0][k];
      float4 h1 = *(const float4*)&Hs[r0 + 1][k];
      float4 h2 = *(const float4*)&Hs[r0 + 2][k];
      float4 h3 = *(const float4*)&Hs[r0 + 3][k];
#define DOT(hv, wv) fmaf((hv).w, (wv).w, fmaf((hv).z, (wv).z, fmaf((hv).y, (wv).y, (hv).x * (wv).x)))
      a0.x += DOT(h0, w0); a0.y += DOT(h0, w1); a0.z += DOT(h0, w2); a0.w += DOT(h0, w3);
      a1.x += DOT(h1, w0); a1.y += DOT(h1, w1); a1.z += DOT(h1, w2); a1.w += DOT(h1, w3);
      a2.x += DOT(h2, w0); a2.y += DOT(h2, w1); a2.z += DOT(h2, w2); a2.w += DOT(h2, w3);
      a3.x += DOT(h3, w0); a3.y += DOT(h3, w1); a3.z += DOT(h3, w2); a3.w += DOT(h3, w3);
#undef DOT
    }
    float4 bv = *(const float4*)(bias + oc0);
    a0.x += bv.x; a0.y += bv.y; a0.z += bv.z; a0.w += bv.w;
    a1.x += bv.x; a1.y += bv.y; a1.z += bv.z; a1.w += bv.w;
    a2.x += bv.x; a2.y += bv.y; a2.z += bv.z; a2.w += bv.w;
    a3.x += bv.x; a3.y += bv.y; a3.z += bv.z; a3.w += bv.w;
    if (r0 + 0 < nr) *(float4*)(out + (size_t)(row0 + r0 + 0) * D + oc0) = a0;
    if (r0 + 1 < nr) *(float4*)(out + (size_t)(row0 + r0 + 1) * D + oc0) = a1;
    if (r0 + 2 < nr) *(float4*)(out + (size_t)(row0 + r0 + 2) * D + oc0) = a2;
    if (r0 + 3 < nr) *(float4*)(out + (size_t)(row0 + r0 + 3) * D + oc0) = a3;
  }
}

extern "C" void kernel_launch(void* const* d_in, const int* in_sizes, int n_in,
                              void* d_out, int out_size, void* d_ws, size_t ws_size,
                              hipStream_t stream) {
  const float* x = (const float*)d_in[0];
  const int* src = (const int*)d_in[1];
  const int* dst = (const int*)d_in[2];
  const float* W = (const float*)d_in[3];
  const float* b = (const float*)d_in[4];
  float* out = (float*)d_out;

  const size_t A = 50048;  // ints per slot (aligned)
  const size_t head_ints = 3 * A + 256 + (size_t)N_EDGES;
  const size_t need_full = head_ints * sizeof(int) +
                           (size_t)N_NODES * D * sizeof(unsigned short);

  if (ws_size >= need_full) {
    int* counts     = (int*)d_ws;
    int* offsets    = counts + A;
    int* cursor     = offsets + A;
    int* blockSums  = cursor + A;
    int* esrc       = blockSums + 256;
    unsigned short* y = (unsigned short*)(esrc + N_EDGES);

    hipMemsetAsync(counts, 0, N_NODES * sizeof(int), stream);
    hist_kernel<<<(N_EDGES + 255) / 256, 256, 0, stream>>>(dst, counts);
    reduce_kernel<<<SBLK, 256, 0, stream>>>(counts, blockSums);
    scan_kernel2<<<SBLK, 256, 0, stream>>>(counts, blockSums, offsets, cursor);
    fill_kernel<<<(N_EDGES + 255) / 256, 256, 0, stream>>>(src, dst, cursor, esrc);
    gemm_xw<<<(N_NODES + 127) / 128, 256, 0, stream>>>(x, W, y);
    gather_ybf_kernel<<<(N_NODES + 3) / 4, 256, 0, stream>>>(y, esrc, offsets, b, out);
  } else {
    hipMemsetAsync(out, 0, (size_t)N_NODES * D * sizeof(float), stream);
    scatter_kernel<<<N_EDGES / 4, 256, 0, stream>>>(x, src, dst, out);
    transform_kernel<<<(N_NODES + 63) / 64, 256, 0, stream>>>(out, W, b);
  }
}